// Round 4
// baseline (436.175 us; speedup 1.0000x reference)
//
#include <hip/hip_runtime.h>
#include <cstdint>
#include <cstddef>

#define D_MODEL 1024
#define N_HEADS 16
#define HEAD_DIM 64
#define BATCH 4
#define SEQ 2048
#define M_TOTAL (BATCH * SEQ)   // 8192

typedef __attribute__((ext_vector_type(8))) short bf16x8;    // 8 bf16 = 4 VGPRs
typedef __attribute__((ext_vector_type(4))) float f32x4;
typedef __attribute__((ext_vector_type(16))) float f32x16;

// scale = 1/sqrt(64) * log2(e), folded into Q projection (softmax in exp2 domain)
#define Q_SCALE 0.18033688011112042f

__device__ __forceinline__ unsigned short f2bu(float f) {   // RNE
    union { float f; unsigned u; } x; x.f = f;
    unsigned r = x.u + 0x7FFFu + ((x.u >> 16) & 1u);
    return (unsigned short)(r >> 16);
}

__device__ __forceinline__ void async16(void* lds, const void* g) {
    __builtin_amdgcn_global_load_lds(
        (const __attribute__((address_space(1))) void*)g,
        (__attribute__((address_space(3))) void*)lds, 16, 0, 0);
}

// ---------------------------------------------------------------------------
// One fused fp32 -> bf16 cast for x + 4 weights (contiguous dst in ws).
// ---------------------------------------------------------------------------
__global__ __launch_bounds__(256) void cast_all(const float* __restrict__ x,
                                                const float* __restrict__ wq,
                                                const float* __restrict__ wk,
                                                const float* __restrict__ wv,
                                                const float* __restrict__ wo,
                                                unsigned short* __restrict__ dst) {
    const size_t NE = (size_t)M_TOTAL * D_MODEL;
    const size_t WE = (size_t)D_MODEL * D_MODEL;
    size_t i4 = (size_t)blockIdx.x * 256 + threadIdx.x;
    size_t e = i4 * 4;
    const float* src; size_t off;
    if (e < NE) { src = x; off = e; }
    else {
        size_t t = e - NE;
        int r = (int)(t / WE); off = t - (size_t)r * WE;
        src = (r == 0) ? wq : (r == 1) ? wk : (r == 2) ? wv : wo;
    }
    float4 v = *(const float4*)(src + off);
    ushort4 o;
    o.x = f2bu(v.x); o.y = f2bu(v.y); o.z = f2bu(v.z); o.w = f2bu(v.w);
    ((ushort4*)dst)[i4] = o;
}

// ---------------------------------------------------------------------------
// Fused Q/K/V projection. sel 0: Q (pre-scaled by Q_SCALE), sel 1: K,
// sel 2: V written TRANSPOSED into Vt[bh][d][s] (folds transpose_v away).
// m97-style: 128x128 tile, BK=32, global_load_lds(16B), XOR chunk swizzle.
// ---------------------------------------------------------------------------
__global__ __launch_bounds__(256) void qkv_gemm(const unsigned short* __restrict__ X,
                                                const unsigned short* __restrict__ W0,
                                                const unsigned short* __restrict__ W1,
                                                const unsigned short* __restrict__ W2,
                                                unsigned short* __restrict__ Y0,
                                                unsigned short* __restrict__ Y1,
                                                unsigned short* __restrict__ Vt) {
    __shared__ short As[128 * 32];
    __shared__ short Bs[128 * 32];

    const int sel = blockIdx.x >> 3;
    const unsigned short* W = (sel == 0) ? W0 : (sel == 1) ? W1 : W2;
    const float scl = (sel == 0) ? Q_SCALE : 1.0f;

    const int tid = threadIdx.x;
    const int w = tid >> 6, lane = tid & 63, quad = lane >> 4, l15 = lane & 15;
    const int wm = w & 1, wn = w >> 1;
    const int rowBase = blockIdx.y * 128;
    const int colBase = (blockIdx.x & 7) * 128;

    f32x4 acc[4][4];
#pragma unroll
    for (int mi = 0; mi < 4; ++mi)
#pragma unroll
        for (int ni = 0; ni < 4; ++ni)
#pragma unroll
            for (int e = 0; e < 4; ++e) acc[mi][ni][e] = 0.f;

    for (int k0 = 0; k0 < 1024; k0 += 32) {
        __syncthreads();
#pragma unroll
        for (int l = 0; l < 2; ++l) {
            int c = tid + l * 256;
            int row = c >> 2, ccs = c & 3;
            int cc = ccs ^ ((row >> 1) & 3);
            async16((char*)As + c * 16, X + (size_t)(rowBase + row) * 1024 + k0 + cc * 8);
            async16((char*)Bs + c * 16, W + (size_t)(colBase + row) * 1024 + k0 + cc * 8);
        }
        __syncthreads();

        bf16x8 a[4], b[4];
#pragma unroll
        for (int mi = 0; mi < 4; ++mi) {
            int r = wm * 64 + mi * 16 + l15;
            int slot = quad ^ ((r >> 1) & 3);
            a[mi] = *(const bf16x8*)&As[r * 32 + slot * 8];
        }
#pragma unroll
        for (int ni = 0; ni < 4; ++ni) {
            int r = wn * 64 + ni * 16 + l15;
            int slot = quad ^ ((r >> 1) & 3);
            b[ni] = *(const bf16x8*)&Bs[r * 32 + slot * 8];
        }
#pragma unroll
        for (int mi = 0; mi < 4; ++mi)
#pragma unroll
            for (int ni = 0; ni < 4; ++ni)
                acc[mi][ni] = __builtin_amdgcn_mfma_f32_16x16x32_bf16(a[mi], b[ni], acc[mi][ni], 0, 0, 0);
    }

    if (sel != 2) {
        unsigned short* Y = (sel == 0) ? Y0 : Y1;
#pragma unroll
        for (int mi = 0; mi < 4; ++mi)
#pragma unroll
            for (int ni = 0; ni < 4; ++ni)
#pragma unroll
                for (int reg = 0; reg < 4; ++reg) {
                    int row = rowBase + wm * 64 + mi * 16 + quad * 4 + reg;
                    int col = colBase + wn * 64 + ni * 16 + l15;
                    Y[(size_t)row * 1024 + col] = f2bu(acc[mi][ni][reg] * scl);
                }
    } else {
        // transposed V write: Vt[((b*16+h)*64+d)*SEQ + s], 4 consecutive s per store
#pragma unroll
        for (int mi = 0; mi < 4; ++mi) {
            int row0 = rowBase + wm * 64 + mi * 16 + quad * 4;   // reg 0 row
            int bb = row0 >> 11;
            int s0 = row0 & 2047;
#pragma unroll
            for (int ni = 0; ni < 4; ++ni) {
                int col = colBase + wn * 64 + ni * 16 + l15;
                int hh = col >> 6, dd = col & 63;
                ushort4 pk;
                pk.x = f2bu(acc[mi][ni][0]); pk.y = f2bu(acc[mi][ni][1]);
                pk.z = f2bu(acc[mi][ni][2]); pk.w = f2bu(acc[mi][ni][3]);
                *(ushort4*)(Vt + (((size_t)bb * 16 + hh) * 64 + dd) * SEQ + s0) = pk;
            }
        }
    }
}

// ---------------------------------------------------------------------------
// Output projection: out[M,1024] = CTX @ Wo^T, fp32 out.
// ---------------------------------------------------------------------------
__global__ __launch_bounds__(256) void out_gemm(const unsigned short* __restrict__ X,
                                                const unsigned short* __restrict__ W,
                                                float* __restrict__ Y) {
    __shared__ short As[128 * 32];
    __shared__ short Bs[128 * 32];

    const int tid = threadIdx.x;
    const int w = tid >> 6, lane = tid & 63, quad = lane >> 4, l15 = lane & 15;
    const int wm = w & 1, wn = w >> 1;
    const int rowBase = blockIdx.y * 128;
    const int colBase = blockIdx.x * 128;

    f32x4 acc[4][4];
#pragma unroll
    for (int mi = 0; mi < 4; ++mi)
#pragma unroll
        for (int ni = 0; ni < 4; ++ni)
#pragma unroll
            for (int e = 0; e < 4; ++e) acc[mi][ni][e] = 0.f;

    for (int k0 = 0; k0 < 1024; k0 += 32) {
        __syncthreads();
#pragma unroll
        for (int l = 0; l < 2; ++l) {
            int c = tid + l * 256;
            int row = c >> 2, ccs = c & 3;
            int cc = ccs ^ ((row >> 1) & 3);
            async16((char*)As + c * 16, X + (size_t)(rowBase + row) * 1024 + k0 + cc * 8);
            async16((char*)Bs + c * 16, W + (size_t)(colBase + row) * 1024 + k0 + cc * 8);
        }
        __syncthreads();

        bf16x8 a[4], b[4];
#pragma unroll
        for (int mi = 0; mi < 4; ++mi) {
            int r = wm * 64 + mi * 16 + l15;
            int slot = quad ^ ((r >> 1) & 3);
            a[mi] = *(const bf16x8*)&As[r * 32 + slot * 8];
        }
#pragma unroll
        for (int ni = 0; ni < 4; ++ni) {
            int r = wn * 64 + ni * 16 + l15;
            int slot = quad ^ ((r >> 1) & 3);
            b[ni] = *(const bf16x8*)&Bs[r * 32 + slot * 8];
        }
#pragma unroll
        for (int mi = 0; mi < 4; ++mi)
#pragma unroll
            for (int ni = 0; ni < 4; ++ni)
                acc[mi][ni] = __builtin_amdgcn_mfma_f32_16x16x32_bf16(a[mi], b[ni], acc[mi][ni], 0, 0, 0);
    }

#pragma unroll
    for (int mi = 0; mi < 4; ++mi)
#pragma unroll
        for (int ni = 0; ni < 4; ++ni)
#pragma unroll
            for (int reg = 0; reg < 4; ++reg) {
                int row = rowBase + wm * 64 + mi * 16 + quad * 4 + reg;
                int col = colBase + wn * 64 + ni * 16 + l15;
                Y[(size_t)row * 1024 + col] = acc[mi][ni][reg];
            }
}

// ---------------------------------------------------------------------------
// Flash attention, 32x32x16 MFMA, St = K Q^T (query = lane index -> per-lane
// softmax state). This revision: KVBLK=128 --
//   * pairing restored: block (bh,pid) handles q-tiles {15-pid, pid} ->
//     exactly 17 k-iterations of 128 keys each (perfect load balance).
//   * grid (64 bh, 8 pid): same-bh blocks land on one XCD (ids differ by
//     64, 64%8==0) -> keeps round-3's 4x FETCH reduction.
//   * one barrier per 128 keys (double-buffered K/V, 66KB LDS, 2 blk/CU).
//   * diagonal tile: wave-uniform sub-tile guards (nT=w+1 of 4 QK tiles,
//     nt=2(w+1) of 8 PV slots) -> balanced triangle, no wasted MFMA.
//   * 4-chain partial sums for the softmax denominator (depth 16+2 vs 64).
//   * retains: defer-max THR=8, v_cvt_pk pack, allSeq fast path, setprio.
// ---------------------------------------------------------------------------
__global__ __launch_bounds__(256) void flash32(const unsigned short* __restrict__ Q,
                                               const unsigned short* __restrict__ K,
                                               const unsigned short* __restrict__ Vt,
                                               const int* __restrict__ mask,
                                               unsigned short* __restrict__ CTX) {
    __shared__ short lds[32768];           // K dbuf @0 (2x16KB), V dbuf @32768B (2x16KB)
    __shared__ float biasS[2][128];
    __shared__ int allokT[2][2];
    __shared__ int okW[4];

    const int bh = blockIdx.x;             // 0..63 (same-bh blocks share an XCD)
    const int pid = blockIdx.y;            // 0..7
    const int b = bh >> 4;
    const int tid = threadIdx.x;
    const int w = tid >> 6, lane = tid & 63, l31 = lane & 31, lane5 = lane >> 5;

    const size_t qkBase = (size_t)b * SEQ * D_MODEL + (size_t)(bh & 15) * HEAD_DIM;
    const size_t vtBase = (size_t)bh * HEAD_DIM * SEQ;

    // ---- attention_mask is k-loop invariant: scan it once per block ----
    {
        int ok = 1;
        for (int i = tid; i < SEQ; i += 256) ok &= (mask[b * SEQ + i] != 0);
        unsigned long long bal = __ballot(ok != 0);
        if (lane == 0) okW[w] = (bal == ~0ull) ? 1 : 0;
    }
    __syncthreads();
    const int allSeq = okW[0] & okW[1] & okW[2] & okW[3];   // block-uniform

    // per-thread staging constants (chunk c = tid + l*256, l=0..3)
    // K tile: 128 rows(key) x 64 dim shorts, 8 slots/row, row bitswap23.
    // V tile:  64 rows(d)  x 128 key shorts, 16 slots/row.
    int stcK[4], stjK[4], stpV[4], stcV[4];
#pragma unroll
    for (int l = 0; l < 4; ++l) {
        int c = tid + l * 256;
        int pK = c >> 3, slK = c & 7;
        stcK[l] = slK ^ (pK & 7);
        stjK[l] = (pK & 0xF3) | ((pK & 4) << 1) | ((pK & 8) >> 1);  // swap bits 2,3
        int pV = c >> 4, slV = c & 15;
        stpV[l] = pV;
        stcV[l] = slV ^ (pV & 15);
    }

    for (int phase = 0; phase < 2; ++phase) {
        const int qt = phase ? pid : 15 - pid;   // 128-row q-tile index (0..15)
        const int q0 = qt * 128;
        const int iq = q0 + w * 32 + l31;        // this lane's query row

        // Q fragments direct from global: B[n=i=l31][k=lane5*8+jj]
        bf16x8 qf[4];
#pragma unroll
        for (int ks = 0; ks < 4; ++ks)
            qf[ks] = *(const bf16x8*)(Q + qkBase + (size_t)iq * D_MODEL + ks * 16 + lane5 * 8);

        float mv = -INFINITY, lv = 0.f;
        f32x16 Ot[2];
#pragma unroll
        for (int dt = 0; dt < 2; ++dt)
#pragma unroll
            for (int e = 0; e < 16; ++e) Ot[dt][e] = 0.f;

        uint4 kreg[4], vreg[4];
        int mreg = 1;
        // prefetch tile 0 (128 keys)
#pragma unroll
        for (int l = 0; l < 4; ++l) {
            kreg[l] = *(const uint4*)(K + qkBase + (size_t)stjK[l] * D_MODEL + stcK[l] * 8);
            vreg[l] = *(const uint4*)(Vt + vtBase + (size_t)stpV[l] * SEQ + stcV[l] * 8);
        }
        if (!allSeq && tid < 128) mreg = mask[b * SEQ + tid];

        for (int kt = 0; kt <= qt; ++kt) {
            const int k0 = kt * 128;
            const int buf = kt & 1;
            char* Kb = (char*)lds + buf * 16384;
            char* Vb = (char*)lds + 32768 + buf * 16384;
            // ---- stage tile kt (regs -> LDS), prefetch kt+1 -------------
#pragma unroll
            for (int l = 0; l < 4; ++l) {
                int c = tid + l * 256;
                *(uint4*)(Kb + c * 16) = kreg[l];
                *(uint4*)(Vb + c * 16) = vreg[l];
            }
            if (!allSeq && tid < 128) {
                biasS[buf][tid] = mreg ? 0.f : -INFINITY;
                unsigned long long bal = __ballot(mreg != 0);
                if (lane == 0) allokT[buf][w] = (bal == ~0ull) ? 1 : 0;
            }
            if (kt < qt) {                   // prefetch next tile (overlaps compute)
                const int kn = k0 + 128;
#pragma unroll
                for (int l = 0; l < 4; ++l) {
                    kreg[l] = *(const uint4*)(K + qkBase + (size_t)(kn + stjK[l]) * D_MODEL + stcK[l] * 8);
                    vreg[l] = *(const uint4*)(Vt + vtBase + (size_t)stpV[l] * SEQ + kn + stcV[l] * 8);
                }
                if (!allSeq && tid < 128) mreg = mask[b * SEQ + kn + tid];
            }
            __syncthreads();                 // buf visible; buf reuse fenced by barrier(kt+1)

            const short* Ks = (const short*)((char*)lds + buf * 16384);
            const short* Vs = (const short*)((char*)lds + 32768 + buf * 16384);

            // wave-uniform active range (diagonal tile triangle)
            const int kHi = q0 + 32 * w + 31 - k0;          // >= 31 always
            const int nT = (kHi >> 5) >= 3 ? 4 : (kHi >> 5) + 1;   // active 32-key QK sub-tiles
            const int nt = (kHi >> 4) >= 7 ? 8 : (kHi >> 4) + 1;   // active 16-key PV slots

            // ---- St = K Q^T (4 sub-tiles x 4 MFMAs) ---------------------
            f32x16 St[4];
            __builtin_amdgcn_s_setprio(1);
#pragma unroll
            for (int T = 0; T < 4; ++T) {
                if (T < nT) {
#pragma unroll
                    for (int e = 0; e < 16; ++e) St[T][e] = 0.f;
#pragma unroll
                    for (int ks = 0; ks < 4; ++ks) {
                        int p = T * 32 + l31;
                        int slot = (ks * 2 + lane5) ^ (p & 7);
                        bf16x8 a = *(const bf16x8*)&Ks[p * 64 + slot * 8];
                        St[T] = __builtin_amdgcn_mfma_f32_32x32x16_bf16(a, qf[ks], St[T], 0, 0, 0);
                    }
                }
            }
            __builtin_amdgcn_s_setprio(0);

            // ---- masking ------------------------------------------------
            if (kHi < 158) {                 // diagonal tile only
#pragma unroll
                for (int T = 0; T < 4; ++T)
                    if (T < nT)
#pragma unroll
                        for (int r = 0; r < 16; ++r) {
                            int j = k0 + 32 * T + 16 * (r >> 3) + 8 * lane5 + (r & 7);
                            if (j > iq) St[T][r] = -INFINITY;
                        }
            }
            if (!allSeq && !(allokT[buf][0] & allokT[buf][1])) {
#pragma unroll
                for (int T = 0; T < 4; ++T)
                    if (T < nT)
#pragma unroll
                        for (int r = 0; r < 16; ++r)
                            St[T][r] += biasS[buf][32 * T + 16 * (r >> 3) + 8 * lane5 + (r & 7)];
            }

            // ---- online softmax (defer-max THR=8, per-lane state) -------
            float tm[4];
#pragma unroll
            for (int T = 0; T < 4; ++T) {
                if (T < nT) {
                    float a0 = fmaxf(fmaxf(St[T][0], St[T][1]), fmaxf(St[T][2], St[T][3]));
                    float a1 = fmaxf(fmaxf(St[T][4], St[T][5]), fmaxf(St[T][6], St[T][7]));
                    float a2 = fmaxf(fmaxf(St[T][8], St[T][9]), fmaxf(St[T][10], St[T][11]));
                    float a3 = fmaxf(fmaxf(St[T][12], St[T][13]), fmaxf(St[T][14], St[T][15]));
                    tm[T] = fmaxf(fmaxf(a0, a1), fmaxf(a2, a3));
                } else tm[T] = -INFINITY;
            }
            float rm = fmaxf(fmaxf(tm[0], tm[1]), fmaxf(tm[2], tm[3]));
            rm = fmaxf(rm, __shfl_xor(rm, 32));
            float mn = fmaxf(mv, rm);
            if (mn > mv + 8.f) {             // rare after warmup (also hits 1st tile)
                float al = exp2f(mv - mn);   // mv=-inf -> 0: correctly zeroes lv/Ot
                lv *= al;
#pragma unroll
                for (int dt = 0; dt < 2; ++dt)
#pragma unroll
                    for (int e = 0; e < 16; ++e) Ot[dt][e] *= al;
                mv = mn;
            }
            // exp2 vs (possibly stale) mv: P bounded by 2^8; -inf scores -> 0
            float rsp[4];
#pragma unroll
            for (int T = 0; T < 4; ++T) {
                rsp[T] = 0.f;
                if (T < nT) {
#pragma unroll
                    for (int r = 0; r < 16; ++r) {
                        float pv = exp2f(St[T][r] - mv);
                        St[T][r] = pv;
                        rsp[T] += pv;
                    }
                }
            }
            float rs = (rsp[0] + rsp[1]) + (rsp[2] + rsp[3]);
            rs += __shfl_xor(rs, 32);
            lv += rs;

            // ---- pack P via v_cvt_pk_bf16_f32 (regs already B-frag order)
            bf16x8 pf[8];
#pragma unroll
            for (int t = 0; t < 8; ++t) {
                if (t < nt) {
                    const int T = t >> 1, hb = t & 1;
                    unsigned u0, u1, u2, u3;
                    asm("v_cvt_pk_bf16_f32 %0, %1, %2" : "=v"(u0)
                        : "v"(St[T][hb * 8 + 0]), "v"(St[T][hb * 8 + 1]));
                    asm("v_cvt_pk_bf16_f32 %0, %1, %2" : "=v"(u1)
                        : "v"(St[T][hb * 8 + 2]), "v"(St[T][hb * 8 + 3]));
                    asm("v_cvt_pk_bf16_f32 %0, %1, %2" : "=v"(u2)
                        : "v"(St[T][hb * 8 + 4]), "v"(St[T][hb * 8 + 5]));
                    asm("v_cvt_pk_bf16_f32 %0, %1, %2" : "=v"(u3)
                        : "v"(St[T][hb * 8 + 6]), "v"(St[T][hb * 8 + 7]));
                    union { unsigned u[4]; bf16x8 v; } pk;
                    pk.u[0] = u0; pk.u[1] = u1; pk.u[2] = u2; pk.u[3] = u3;
                    pf[t] = pk.v;
                }
            }

            // ---- Ot += V^T P^T (up to 16 MFMAs) -------------------------
            __builtin_amdgcn_s_setprio(1);
#pragma unroll
            for (int dt = 0; dt < 2; ++dt)
#pragma unroll
                for (int t = 0; t < 8; ++t) {
                    if (t < nt) {
                        int p = dt * 32 + l31;
                        int slot = (t * 2 + lane5) ^ (p & 15);
                        bf16x8 a = *(const bf16x8*)&Vs[p * 128 + slot * 8];
                        Ot[dt] = __builtin_amdgcn_mfma_f32_32x32x16_bf16(a, pf[t], Ot[dt], 0, 0, 0);
                    }
                }
            __builtin_amdgcn_s_setprio(0);
        }

        // ---- epilogue: normalize, transpose via LDS, coalesced store ----
        __syncthreads();                       // all waves done with K/V buffers
        const float inv = 1.f / lv;
#pragma unroll
        for (int dt = 0; dt < 2; ++dt)
#pragma unroll
            for (int k = 0; k < 8; ++k) {
                int r0 = 2 * k;
                int d = (r0 & 3) + 4 * lane5 + 8 * (r0 >> 2) + 32 * dt;
                unsigned lo = f2bu(Ot[dt][r0] * inv);
                unsigned hi = f2bu(Ot[dt][r0 + 1] * inv);
                *(unsigned*)&lds[(w * 32 + l31) * 72 + d] = lo | (hi << 16);
            }
        __syncthreads();
#pragma unroll
        for (int k = 0; k < 4; ++k) {
            int id = tid + k * 256;
            int r = id >> 3, cc = id & 7;
            uint4 v = *(const uint4*)&lds[r * 72 + cc * 8];
            *(uint4*)(CTX + qkBase + (size_t)(q0 + r) * D_MODEL + cc * 8) = v;
        }
        __syncthreads();                       // protect epilogue reads from next phase's staging
    }
}

// ---------------------------------------------------------------------------
extern "C" void kernel_launch(void* const* d_in, const int* in_sizes, int n_in,
                              void* d_out, int out_size, void* d_ws, size_t ws_size,
                              hipStream_t stream) {
    const float* x  = (const float*)d_in[0];
    const int* mask = (const int*)d_in[1];
    const float* wq = (const float*)d_in[2];
    const float* wk = (const float*)d_in[3];
    const float* wv = (const float*)d_in[4];
    const float* wo = (const float*)d_in[5];
    float* out = (float*)d_out;

    const size_t NE = (size_t)M_TOTAL * D_MODEL;
    const size_t WE = (size_t)D_MODEL * D_MODEL;
    unsigned short* ws  = (unsigned short*)d_ws;
    unsigned short* xb  = ws;
    unsigned short* wqb = xb + NE;
    unsigned short* wkb = wqb + WE;
    unsigned short* wvb = wkb + WE;
    unsigned short* wob = wvb + WE;
    unsigned short* Qb  = wob + WE;
    unsigned short* Kb  = Qb + NE;
    unsigned short* Vtb = Kb + NE;
    unsigned short* CTX = Vtb + NE;

    cast_all<<<(int)((NE + 4 * WE) / 4 / 256), 256, 0, stream>>>(x, wq, wk, wv, wo, ws);

    qkv_gemm<<<dim3(24, M_TOTAL / 128), 256, 0, stream>>>(xb, wqb, wkb, wvb, Qb, Kb, Vtb);

    flash32<<<dim3(64, 8), 256, 0, stream>>>(Qb, Kb, Vtb, mask, CTX);

    out_gemm<<<dim3(D_MODEL / 128, M_TOTAL / 128), 256, 0, stream>>>(CTX, wob, out);
}

// Round 5
// 309.729 us; speedup vs baseline: 1.4082x; 1.4082x over previous
//
#include <hip/hip_runtime.h>
#include <cstdint>
#include <cstddef>

#define D_MODEL 1024
#define N_HEADS 16
#define HEAD_DIM 64
#define BATCH 4
#define SEQ 2048
#define M_TOTAL (BATCH * SEQ)   // 8192

typedef __attribute__((ext_vector_type(8))) short bf16x8;    // 8 bf16 = 4 VGPRs
typedef __attribute__((ext_vector_type(4))) float f32x4;
typedef __attribute__((ext_vector_type(16))) float f32x16;

// scale = 1/sqrt(64) * log2(e), folded into Q projection (softmax in exp2 domain)
#define Q_SCALE 0.18033688011112042f

__device__ __forceinline__ unsigned short f2bu(float f) {   // RNE
    union { float f; unsigned u; } x; x.f = f;
    unsigned r = x.u + 0x7FFFu + ((x.u >> 16) & 1u);
    return (unsigned short)(r >> 16);
}

__device__ __forceinline__ void async16(void* lds, const void* g) {
    __builtin_amdgcn_global_load_lds(
        (const __attribute__((address_space(1))) void*)g,
        (__attribute__((address_space(3))) void*)lds, 16, 0, 0);
}

// ---------------------------------------------------------------------------
// One fused fp32 -> bf16 cast for x + 4 weights (contiguous dst in ws).
// ---------------------------------------------------------------------------
__global__ __launch_bounds__(256) void cast_all(const float* __restrict__ x,
                                                const float* __restrict__ wq,
                                                const float* __restrict__ wk,
                                                const float* __restrict__ wv,
                                                const float* __restrict__ wo,
                                                unsigned short* __restrict__ dst) {
    const size_t NE = (size_t)M_TOTAL * D_MODEL;
    const size_t WE = (size_t)D_MODEL * D_MODEL;
    size_t i4 = (size_t)blockIdx.x * 256 + threadIdx.x;
    size_t e = i4 * 4;
    const float* src; size_t off;
    if (e < NE) { src = x; off = e; }
    else {
        size_t t = e - NE;
        int r = (int)(t / WE); off = t - (size_t)r * WE;
        src = (r == 0) ? wq : (r == 1) ? wk : (r == 2) ? wv : wo;
    }
    float4 v = *(const float4*)(src + off);
    ushort4 o;
    o.x = f2bu(v.x); o.y = f2bu(v.y); o.z = f2bu(v.z); o.w = f2bu(v.w);
    ((ushort4*)dst)[i4] = o;
}

// ---------------------------------------------------------------------------
// Fused Q/K/V projection. sel 0: Q (pre-scaled by Q_SCALE), sel 1: K,
// sel 2: V written TRANSPOSED into Vt[bh][d][s] (folds transpose_v away).
// m97-style: 128x128 tile, BK=32, global_load_lds(16B), XOR chunk swizzle.
// ---------------------------------------------------------------------------
__global__ __launch_bounds__(256) void qkv_gemm(const unsigned short* __restrict__ X,
                                                const unsigned short* __restrict__ W0,
                                                const unsigned short* __restrict__ W1,
                                                const unsigned short* __restrict__ W2,
                                                unsigned short* __restrict__ Y0,
                                                unsigned short* __restrict__ Y1,
                                                unsigned short* __restrict__ Vt) {
    __shared__ short As[128 * 32];
    __shared__ short Bs[128 * 32];

    const int sel = blockIdx.x >> 3;
    const unsigned short* W = (sel == 0) ? W0 : (sel == 1) ? W1 : W2;
    const float scl = (sel == 0) ? Q_SCALE : 1.0f;

    const int tid = threadIdx.x;
    const int w = tid >> 6, lane = tid & 63, quad = lane >> 4, l15 = lane & 15;
    const int wm = w & 1, wn = w >> 1;
    const int rowBase = blockIdx.y * 128;
    const int colBase = (blockIdx.x & 7) * 128;

    f32x4 acc[4][4];
#pragma unroll
    for (int mi = 0; mi < 4; ++mi)
#pragma unroll
        for (int ni = 0; ni < 4; ++ni)
#pragma unroll
            for (int e = 0; e < 4; ++e) acc[mi][ni][e] = 0.f;

    for (int k0 = 0; k0 < 1024; k0 += 32) {
        __syncthreads();
#pragma unroll
        for (int l = 0; l < 2; ++l) {
            int c = tid + l * 256;
            int row = c >> 2, ccs = c & 3;
            int cc = ccs ^ ((row >> 1) & 3);
            async16((char*)As + c * 16, X + (size_t)(rowBase + row) * 1024 + k0 + cc * 8);
            async16((char*)Bs + c * 16, W + (size_t)(colBase + row) * 1024 + k0 + cc * 8);
        }
        __syncthreads();

        bf16x8 a[4], b[4];
#pragma unroll
        for (int mi = 0; mi < 4; ++mi) {
            int r = wm * 64 + mi * 16 + l15;
            int slot = quad ^ ((r >> 1) & 3);
            a[mi] = *(const bf16x8*)&As[r * 32 + slot * 8];
        }
#pragma unroll
        for (int ni = 0; ni < 4; ++ni) {
            int r = wn * 64 + ni * 16 + l15;
            int slot = quad ^ ((r >> 1) & 3);
            b[ni] = *(const bf16x8*)&Bs[r * 32 + slot * 8];
        }
#pragma unroll
        for (int mi = 0; mi < 4; ++mi)
#pragma unroll
            for (int ni = 0; ni < 4; ++ni)
                acc[mi][ni] = __builtin_amdgcn_mfma_f32_16x16x32_bf16(a[mi], b[ni], acc[mi][ni], 0, 0, 0);
    }

    if (sel != 2) {
        unsigned short* Y = (sel == 0) ? Y0 : Y1;
#pragma unroll
        for (int mi = 0; mi < 4; ++mi)
#pragma unroll
            for (int ni = 0; ni < 4; ++ni)
#pragma unroll
                for (int reg = 0; reg < 4; ++reg) {
                    int row = rowBase + wm * 64 + mi * 16 + quad * 4 + reg;
                    int col = colBase + wn * 64 + ni * 16 + l15;
                    Y[(size_t)row * 1024 + col] = f2bu(acc[mi][ni][reg] * scl);
                }
    } else {
        // transposed V write: Vt[((b*16+h)*64+d)*SEQ + s], 4 consecutive s per store
#pragma unroll
        for (int mi = 0; mi < 4; ++mi) {
            int row0 = rowBase + wm * 64 + mi * 16 + quad * 4;   // reg 0 row
            int bb = row0 >> 11;
            int s0 = row0 & 2047;
#pragma unroll
            for (int ni = 0; ni < 4; ++ni) {
                int col = colBase + wn * 64 + ni * 16 + l15;
                int hh = col >> 6, dd = col & 63;
                ushort4 pk;
                pk.x = f2bu(acc[mi][ni][0]); pk.y = f2bu(acc[mi][ni][1]);
                pk.z = f2bu(acc[mi][ni][2]); pk.w = f2bu(acc[mi][ni][3]);
                *(ushort4*)(Vt + (((size_t)bb * 16 + hh) * 64 + dd) * SEQ + s0) = pk;
            }
        }
    }
}

// ---------------------------------------------------------------------------
// Output projection: out[M,1024] = CTX @ Wo^T, fp32 out.
// ---------------------------------------------------------------------------
__global__ __launch_bounds__(256) void out_gemm(const unsigned short* __restrict__ X,
                                                const unsigned short* __restrict__ W,
                                                float* __restrict__ Y) {
    __shared__ short As[128 * 32];
    __shared__ short Bs[128 * 32];

    const int tid = threadIdx.x;
    const int w = tid >> 6, lane = tid & 63, quad = lane >> 4, l15 = lane & 15;
    const int wm = w & 1, wn = w >> 1;
    const int rowBase = blockIdx.y * 128;
    const int colBase = blockIdx.x * 128;

    f32x4 acc[4][4];
#pragma unroll
    for (int mi = 0; mi < 4; ++mi)
#pragma unroll
        for (int ni = 0; ni < 4; ++ni)
#pragma unroll
            for (int e = 0; e < 4; ++e) acc[mi][ni][e] = 0.f;

    for (int k0 = 0; k0 < 1024; k0 += 32) {
        __syncthreads();
#pragma unroll
        for (int l = 0; l < 2; ++l) {
            int c = tid + l * 256;
            int row = c >> 2, ccs = c & 3;
            int cc = ccs ^ ((row >> 1) & 3);
            async16((char*)As + c * 16, X + (size_t)(rowBase + row) * 1024 + k0 + cc * 8);
            async16((char*)Bs + c * 16, W + (size_t)(colBase + row) * 1024 + k0 + cc * 8);
        }
        __syncthreads();

        bf16x8 a[4], b[4];
#pragma unroll
        for (int mi = 0; mi < 4; ++mi) {
            int r = wm * 64 + mi * 16 + l15;
            int slot = quad ^ ((r >> 1) & 3);
            a[mi] = *(const bf16x8*)&As[r * 32 + slot * 8];
        }
#pragma unroll
        for (int ni = 0; ni < 4; ++ni) {
            int r = wn * 64 + ni * 16 + l15;
            int slot = quad ^ ((r >> 1) & 3);
            b[ni] = *(const bf16x8*)&Bs[r * 32 + slot * 8];
        }
#pragma unroll
        for (int mi = 0; mi < 4; ++mi)
#pragma unroll
            for (int ni = 0; ni < 4; ++ni)
                acc[mi][ni] = __builtin_amdgcn_mfma_f32_16x16x32_bf16(a[mi], b[ni], acc[mi][ni], 0, 0, 0);
    }

#pragma unroll
    for (int mi = 0; mi < 4; ++mi)
#pragma unroll
        for (int ni = 0; ni < 4; ++ni)
#pragma unroll
            for (int reg = 0; reg < 4; ++reg) {
                int row = rowBase + wm * 64 + mi * 16 + quad * 4 + reg;
                int col = colBase + wn * 64 + ni * 16 + l15;
                Y[(size_t)row * 1024 + col] = acc[mi][ni][reg];
            }
}

// ---------------------------------------------------------------------------
// Flash attention, 32x32x16 MFMA, St = K Q^T (query = lane index -> per-lane
// softmax state). Round-5 recombination of verified wins:
//   * KVBLK=64, St[2]: ~100 VGPR, 33KB LDS -> 2 blocks/CU co-resident (r2).
//   * paired q-tiles {15-pid, pid}: exactly 36 k-iters/block, perfect
//     static balance (r2; removes r3's ~18% imbalance).
//   * grid (64 bh, 8 pid): same-bh ids differ by 64 == 0 mod 8 -> one XCD
//     per bh -> 4x FETCH reduction (r3, verified).
//   * double-buffered K/V, ONE barrier per tile (r3 schedule, race-free).
//   * wave-uniform triangle guards nT/nt on the diagonal (r4, verified).
//   * retains: defer-max THR=8, v_cvt_pk pack, allSeq fast path, setprio.
// ---------------------------------------------------------------------------
__global__ __launch_bounds__(256) void flash32(const unsigned short* __restrict__ Q,
                                               const unsigned short* __restrict__ K,
                                               const unsigned short* __restrict__ Vt,
                                               const int* __restrict__ mask,
                                               unsigned short* __restrict__ CTX) {
    __shared__ short lds[16384];           // K dbuf [0..8191], V dbuf [8192..16383] (shorts)
    __shared__ float biasS[2][64];
    __shared__ int allokS[2];
    __shared__ int okW[4];

    const int bh = blockIdx.x;             // 0..63 (same-bh blocks share an XCD)
    const int pid = blockIdx.y;            // 0..7
    const int b = bh >> 4;
    const int tid = threadIdx.x;
    const int w = tid >> 6, lane = tid & 63, l31 = lane & 31, lane5 = lane >> 5;

    const size_t qkBase = (size_t)b * SEQ * D_MODEL + (size_t)(bh & 15) * HEAD_DIM;
    const size_t vtBase = (size_t)bh * HEAD_DIM * SEQ;

    // ---- attention_mask is k-loop invariant: scan it once per block ----
    {
        int ok = 1;
        for (int i = tid; i < SEQ; i += 256) ok &= (mask[b * SEQ + i] != 0);
        unsigned long long bal = __ballot(ok != 0);
        if (lane == 0) okW[w] = (bal == ~0ull) ? 1 : 0;
    }
    __syncthreads();
    const int allSeq = okW[0] & okW[1] & okW[2] & okW[3];   // block-uniform

    // per-thread staging constants (chunk c = tid + l*256)
    int stp[2], stcc[2], stj[2];
#pragma unroll
    for (int l = 0; l < 2; ++l) {
        int c = tid + l * 256;
        int p = c >> 3, sl = c & 7;
        stp[l] = p;
        stcc[l] = sl ^ (p & 7);                                   // bank swizzle
        stj[l] = (p & 0x33) | ((p & 4) << 1) | ((p & 8) >> 1);    // swap bits 2,3
    }

    for (int phase = 0; phase < 2; ++phase) {
        const int qt = phase ? pid : 15 - pid;
        const int q0 = qt * 128;
        const int iq = q0 + w * 32 + l31;      // this lane's query row

        // Q fragments direct from global: B[n=i=l31][k=lane5*8+jj]
        bf16x8 qf[4];
#pragma unroll
        for (int ks = 0; ks < 4; ++ks)
            qf[ks] = *(const bf16x8*)(Q + qkBase + (size_t)iq * D_MODEL + ks * 16 + lane5 * 8);

        float mv = -INFINITY, lv = 0.f;
        f32x16 Ot[2];
#pragma unroll
        for (int dt = 0; dt < 2; ++dt)
#pragma unroll
            for (int e = 0; e < 16; ++e) Ot[dt][e] = 0.f;

        const int ktmax = 2 * qt + 1;

        uint4 kreg[2], vreg[2];
        int mreg = 1;
        // prefetch tile 0
#pragma unroll
        for (int l = 0; l < 2; ++l) {
            kreg[l] = *(const uint4*)(K + qkBase + (size_t)stj[l] * D_MODEL + stcc[l] * 8);
            vreg[l] = *(const uint4*)(Vt + vtBase + (size_t)stp[l] * SEQ + stcc[l] * 8);
        }
        if (!allSeq && tid < 64) mreg = mask[b * SEQ + tid];

        for (int kt = 0; kt <= ktmax; ++kt) {
            const int k0 = kt * 64;
            const int buf = kt & 1;
            // ---- stage tile kt into buf (regs -> LDS), prefetch kt+1 ----
#pragma unroll
            for (int l = 0; l < 2; ++l) {
                int c = tid + l * 256;
                *(uint4*)((char*)lds + buf * 8192 + c * 16) = kreg[l];
                *(uint4*)((char*)lds + 16384 + buf * 8192 + c * 16) = vreg[l];
            }
            if (!allSeq && tid < 64) {
                biasS[buf][tid] = mreg ? 0.f : -INFINITY;
                unsigned long long bal = __ballot(mreg != 0);
                if (tid == 0) allokS[buf] = (bal == ~0ull) ? 1 : 0;
            }
            if (kt < ktmax) {                  // prefetch next tile (overlaps compute)
                const int kn = k0 + 64;
#pragma unroll
                for (int l = 0; l < 2; ++l) {
                    kreg[l] = *(const uint4*)(K + qkBase + (size_t)(kn + stj[l]) * D_MODEL + stcc[l] * 8);
                    vreg[l] = *(const uint4*)(Vt + vtBase + (size_t)stp[l] * SEQ + kn + stcc[l] * 8);
                }
                if (!allSeq && tid < 64) mreg = mask[b * SEQ + kn + tid];
            }
            __syncthreads();                   // buf visible; buf reuse fenced by barrier(kt+1)

            if (64 * kt > q0 + 32 * w + 31) continue;   // wave-uniform: tile above causal diag

            const short* Ks = lds + buf * 4096;
            const short* Vs = lds + 8192 + buf * 4096;

            // wave-uniform active range (diagonal tile triangle)
            const int kHi = q0 + 32 * w + 31 - k0;           // >= 0 here
            const int nT = (kHi >= 32) ? 2 : 1;              // active 32-key QK sub-tiles
            const int nt = ((kHi >> 4) >= 3 ? 3 : (kHi >> 4)) + 1;  // active 16-key PV slots

            // ---- St = K Q^T (up to 8 MFMAs) -----------------------------
            f32x16 St[2];
            __builtin_amdgcn_s_setprio(1);
#pragma unroll
            for (int T = 0; T < 2; ++T) {
                if (T < nT) {
#pragma unroll
                    for (int e = 0; e < 16; ++e) St[T][e] = 0.f;
#pragma unroll
                    for (int ks = 0; ks < 4; ++ks) {
                        int p = T * 32 + l31;
                        int slot = (ks * 2 + lane5) ^ (p & 7);
                        bf16x8 a = *(const bf16x8*)&Ks[p * 64 + slot * 8];
                        St[T] = __builtin_amdgcn_mfma_f32_32x32x16_bf16(a, qf[ks], St[T], 0, 0, 0);
                    }
                }
            }
            __builtin_amdgcn_s_setprio(0);

            // ---- masking ------------------------------------------------
            const bool partial = (k0 + 63 > q0 + 32 * w);
            if (partial) {
#pragma unroll
                for (int T = 0; T < 2; ++T)
                    if (T < nT)
#pragma unroll
                        for (int r = 0; r < 16; ++r) {
                            int j = k0 + 32 * T + 16 * (r >> 3) + 8 * lane5 + (r & 7);
                            if (j > iq) St[T][r] = -INFINITY;
                        }
            }
            if (!allSeq && !allokS[buf]) {
#pragma unroll
                for (int T = 0; T < 2; ++T)
                    if (T < nT)
#pragma unroll
                        for (int r = 0; r < 16; ++r)
                            St[T][r] += biasS[buf][32 * T + 16 * (r >> 3) + 8 * lane5 + (r & 7)];
            }

            // ---- online softmax (defer-max THR=8, per-lane state) -------
            float tm[2];
#pragma unroll
            for (int T = 0; T < 2; ++T) {
                if (T < nT) {
                    float a0 = fmaxf(fmaxf(St[T][0], St[T][1]), fmaxf(St[T][2], St[T][3]));
                    float a1 = fmaxf(fmaxf(St[T][4], St[T][5]), fmaxf(St[T][6], St[T][7]));
                    float a2 = fmaxf(fmaxf(St[T][8], St[T][9]), fmaxf(St[T][10], St[T][11]));
                    float a3 = fmaxf(fmaxf(St[T][12], St[T][13]), fmaxf(St[T][14], St[T][15]));
                    tm[T] = fmaxf(fmaxf(a0, a1), fmaxf(a2, a3));
                } else tm[T] = -INFINITY;
            }
            float rm = fmaxf(tm[0], tm[1]);
            rm = fmaxf(rm, __shfl_xor(rm, 32));
            float mn = fmaxf(mv, rm);
            if (mn > mv + 8.f) {               // rare after warmup (also hits 1st tile)
                float al = exp2f(mv - mn);     // mv=-inf -> 0: correctly zeroes lv/Ot
                lv *= al;
#pragma unroll
                for (int dt = 0; dt < 2; ++dt)
#pragma unroll
                    for (int e = 0; e < 16; ++e) Ot[dt][e] *= al;
                mv = mn;
            }
            // exp2 vs (possibly stale) mv: P bounded by 2^8; -inf scores -> 0
            float rsp[2] = {0.f, 0.f};
#pragma unroll
            for (int T = 0; T < 2; ++T) {
                if (T < nT) {
#pragma unroll
                    for (int r = 0; r < 16; ++r) {
                        float pv = exp2f(St[T][r] - mv);
                        St[T][r] = pv;
                        rsp[T] += pv;
                    }
                }
            }
            float rs = rsp[0] + rsp[1];
            rs += __shfl_xor(rs, 32);
            lv += rs;

            // ---- pack P via v_cvt_pk_bf16_f32 (regs already B-frag order)
            bf16x8 pf[4];
#pragma unroll
            for (int t = 0; t < 4; ++t) {
                if (t < nt) {
                    const int T = t >> 1, hb = t & 1;
                    unsigned u0, u1, u2, u3;
                    asm("v_cvt_pk_bf16_f32 %0, %1, %2" : "=v"(u0)
                        : "v"(St[T][hb * 8 + 0]), "v"(St[T][hb * 8 + 1]));
                    asm("v_cvt_pk_bf16_f32 %0, %1, %2" : "=v"(u1)
                        : "v"(St[T][hb * 8 + 2]), "v"(St[T][hb * 8 + 3]));
                    asm("v_cvt_pk_bf16_f32 %0, %1, %2" : "=v"(u2)
                        : "v"(St[T][hb * 8 + 4]), "v"(St[T][hb * 8 + 5]));
                    asm("v_cvt_pk_bf16_f32 %0, %1, %2" : "=v"(u3)
                        : "v"(St[T][hb * 8 + 6]), "v"(St[T][hb * 8 + 7]));
                    union { unsigned u[4]; bf16x8 v; } pk;
                    pk.u[0] = u0; pk.u[1] = u1; pk.u[2] = u2; pk.u[3] = u3;
                    pf[t] = pk.v;
                }
            }

            // ---- Ot += V^T P^T (up to 8 MFMAs) --------------------------
            __builtin_amdgcn_s_setprio(1);
#pragma unroll
            for (int dt = 0; dt < 2; ++dt)
#pragma unroll
                for (int t = 0; t < 4; ++t) {
                    if (t < nt) {
                        int p = dt * 32 + l31;
                        int slot = (t * 2 + lane5) ^ (p & 7);
                        bf16x8 a = *(const bf16x8*)&Vs[p * 64 + slot * 8];
                        Ot[dt] = __builtin_amdgcn_mfma_f32_32x32x16_bf16(a, pf[t], Ot[dt], 0, 0, 0);
                    }
                }
            __builtin_amdgcn_s_setprio(0);
        }

        // ---- epilogue: normalize, transpose via LDS, coalesced store ----
        __syncthreads();                       // all waves done with K/V buffers
        const float inv = 1.f / lv;
#pragma unroll
        for (int dt = 0; dt < 2; ++dt)
#pragma unroll
            for (int k = 0; k < 8; ++k) {
                int r0 = 2 * k;
                int d = (r0 & 3) + 4 * lane5 + 8 * (r0 >> 2) + 32 * dt;
                unsigned lo = f2bu(Ot[dt][r0] * inv);
                unsigned hi = f2bu(Ot[dt][r0 + 1] * inv);
                *(unsigned*)&lds[(w * 32 + l31) * 72 + d] = lo | (hi << 16);
            }
        __syncthreads();
#pragma unroll
        for (int k = 0; k < 4; ++k) {
            int id = tid + k * 256;
            int r = id >> 3, cc = id & 7;
            uint4 v = *(const uint4*)&lds[r * 72 + cc * 8];
            *(uint4*)(CTX + qkBase + (size_t)(q0 + r) * D_MODEL + cc * 8) = v;
        }
        __syncthreads();                       // protect epilogue reads from next phase's staging
    }
}

// ---------------------------------------------------------------------------
extern "C" void kernel_launch(void* const* d_in, const int* in_sizes, int n_in,
                              void* d_out, int out_size, void* d_ws, size_t ws_size,
                              hipStream_t stream) {
    const float* x  = (const float*)d_in[0];
    const int* mask = (const int*)d_in[1];
    const float* wq = (const float*)d_in[2];
    const float* wk = (const float*)d_in[3];
    const float* wv = (const float*)d_in[4];
    const float* wo = (const float*)d_in[5];
    float* out = (float*)d_out;

    const size_t NE = (size_t)M_TOTAL * D_MODEL;
    const size_t WE = (size_t)D_MODEL * D_MODEL;
    unsigned short* ws  = (unsigned short*)d_ws;
    unsigned short* xb  = ws;
    unsigned short* wqb = xb + NE;
    unsigned short* wkb = wqb + WE;
    unsigned short* wvb = wkb + WE;
    unsigned short* wob = wvb + WE;
    unsigned short* Qb  = wob + WE;
    unsigned short* Kb  = Qb + NE;
    unsigned short* Vtb = Kb + NE;
    unsigned short* CTX = Vtb + NE;

    cast_all<<<(int)((NE + 4 * WE) / 4 / 256), 256, 0, stream>>>(x, wq, wk, wv, wo, ws);

    qkv_gemm<<<dim3(24, M_TOTAL / 128), 256, 0, stream>>>(xb, wqb, wkb, wvb, Qb, Kb, Vtb);

    flash32<<<dim3(64, 8), 256, 0, stream>>>(Qb, Kb, Vtb, mask, CTX);

    out_gemm<<<dim3(D_MODEL / 128, M_TOTAL / 128), 256, 0, stream>>>(CTX, wob, out);
}

// Round 8
// 306.711 us; speedup vs baseline: 1.4221x; 1.0098x over previous
//
#include <hip/hip_runtime.h>
#include <cstdint>
#include <cstddef>

#define D_MODEL 1024
#define N_HEADS 16
#define HEAD_DIM 64
#define BATCH 4
#define SEQ 2048
#define M_TOTAL (BATCH * SEQ)   // 8192

typedef __attribute__((ext_vector_type(8))) short bf16x8;    // 8 bf16 = 4 VGPRs
typedef __attribute__((ext_vector_type(4))) float f32x4;
typedef __attribute__((ext_vector_type(16))) float f32x16;

// scale = 1/sqrt(64) * log2(e), folded into Q projection (softmax in exp2 domain)
#define Q_SCALE 0.18033688011112042f

__device__ __forceinline__ unsigned short f2bu(float f) {   // RNE
    union { float f; unsigned u; } x; x.f = f;
    unsigned r = x.u + 0x7FFFu + ((x.u >> 16) & 1u);
    return (unsigned short)(r >> 16);
}

__device__ __forceinline__ void async16(void* lds, const void* g) {
    __builtin_amdgcn_global_load_lds(
        (const __attribute__((address_space(1))) void*)g,
        (__attribute__((address_space(3))) void*)lds, 16, 0, 0);
}

// ---------------------------------------------------------------------------
// One fused fp32 -> bf16 cast for x + 4 weights (contiguous dst in ws).
// ---------------------------------------------------------------------------
__global__ __launch_bounds__(256) void cast_all(const float* __restrict__ x,
                                                const float* __restrict__ wq,
                                                const float* __restrict__ wk,
                                                const float* __restrict__ wv,
                                                const float* __restrict__ wo,
                                                unsigned short* __restrict__ dst) {
    const size_t NE = (size_t)M_TOTAL * D_MODEL;
    const size_t WE = (size_t)D_MODEL * D_MODEL;
    size_t i4 = (size_t)blockIdx.x * 256 + threadIdx.x;
    size_t e = i4 * 4;
    const float* src; size_t off;
    if (e < NE) { src = x; off = e; }
    else {
        size_t t = e - NE;
        int r = (int)(t / WE); off = t - (size_t)r * WE;
        src = (r == 0) ? wq : (r == 1) ? wk : (r == 2) ? wv : wo;
    }
    float4 v = *(const float4*)(src + off);
    ushort4 o;
    o.x = f2bu(v.x); o.y = f2bu(v.y); o.z = f2bu(v.z); o.w = f2bu(v.w);
    ((ushort4*)dst)[i4] = o;
}

// ---------------------------------------------------------------------------
// Fused Q/K/V projection. sel 0: Q (pre-scaled by Q_SCALE), sel 1: K,
// sel 2: V written TRANSPOSED into Vt[bh][d][s] (folds transpose_v away).
// m97-style: 128x128 tile, BK=32, global_load_lds(16B), XOR chunk swizzle.
// Round-8: T1 XCD-aware bijective grid remap — all blocks sharing an A
// row-panel (same ty) land on ONE XCD (was: spread over all 8). nwg=1536,
// xcd = id&7, slot = id>>3; ty = xcd*8 + slot/24, tx = slot%24. Bijective.
// ---------------------------------------------------------------------------
__global__ __launch_bounds__(256) void qkv_gemm(const unsigned short* __restrict__ X,
                                                const unsigned short* __restrict__ W0,
                                                const unsigned short* __restrict__ W1,
                                                const unsigned short* __restrict__ W2,
                                                unsigned short* __restrict__ Y0,
                                                unsigned short* __restrict__ Y1,
                                                unsigned short* __restrict__ Vt) {
    __shared__ short As[128 * 32];
    __shared__ short Bs[128 * 32];

    const int id = (int)blockIdx.x + 24 * (int)blockIdx.y;
    const int xcd = id & 7, slot = id >> 3;
    const int ty = xcd * 8 + slot / 24;        // row tile 0..63 (XCD-clustered)
    const int tx = slot % 24;                  // sel*8 + col tile

    const int sel = tx >> 3;
    const unsigned short* W = (sel == 0) ? W0 : (sel == 1) ? W1 : W2;
    const float scl = (sel == 0) ? Q_SCALE : 1.0f;

    const int tid = threadIdx.x;
    const int w = tid >> 6, lane = tid & 63, quad = lane >> 4, l15 = lane & 15;
    const int wm = w & 1, wn = w >> 1;
    const int rowBase = ty * 128;
    const int colBase = (tx & 7) * 128;

    f32x4 acc[4][4];
#pragma unroll
    for (int mi = 0; mi < 4; ++mi)
#pragma unroll
        for (int ni = 0; ni < 4; ++ni)
#pragma unroll
            for (int e = 0; e < 4; ++e) acc[mi][ni][e] = 0.f;

    for (int k0 = 0; k0 < 1024; k0 += 32) {
        __syncthreads();
#pragma unroll
        for (int l = 0; l < 2; ++l) {
            int c = tid + l * 256;
            int row = c >> 2, ccs = c & 3;
            int cc = ccs ^ ((row >> 1) & 3);
            async16((char*)As + c * 16, X + (size_t)(rowBase + row) * 1024 + k0 + cc * 8);
            async16((char*)Bs + c * 16, W + (size_t)(colBase + row) * 1024 + k0 + cc * 8);
        }
        __syncthreads();

        bf16x8 a[4], b[4];
#pragma unroll
        for (int mi = 0; mi < 4; ++mi) {
            int r = wm * 64 + mi * 16 + l15;
            int slt = quad ^ ((r >> 1) & 3);
            a[mi] = *(const bf16x8*)&As[r * 32 + slt * 8];
        }
#pragma unroll
        for (int ni = 0; ni < 4; ++ni) {
            int r = wn * 64 + ni * 16 + l15;
            int slt = quad ^ ((r >> 1) & 3);
            b[ni] = *(const bf16x8*)&Bs[r * 32 + slt * 8];
        }
#pragma unroll
        for (int mi = 0; mi < 4; ++mi)
#pragma unroll
            for (int ni = 0; ni < 4; ++ni)
                acc[mi][ni] = __builtin_amdgcn_mfma_f32_16x16x32_bf16(a[mi], b[ni], acc[mi][ni], 0, 0, 0);
    }

    if (sel != 2) {
        unsigned short* Y = (sel == 0) ? Y0 : Y1;
#pragma unroll
        for (int mi = 0; mi < 4; ++mi)
#pragma unroll
            for (int ni = 0; ni < 4; ++ni)
#pragma unroll
                for (int reg = 0; reg < 4; ++reg) {
                    int row = rowBase + wm * 64 + mi * 16 + quad * 4 + reg;
                    int col = colBase + wn * 64 + ni * 16 + l15;
                    Y[(size_t)row * 1024 + col] = f2bu(acc[mi][ni][reg] * scl);
                }
    } else {
        // transposed V write: Vt[((b*16+h)*64+d)*SEQ + s], 4 consecutive s per store
#pragma unroll
        for (int mi = 0; mi < 4; ++mi) {
            int row0 = rowBase + wm * 64 + mi * 16 + quad * 4;   // reg 0 row
            int bb = row0 >> 11;
            int s0 = row0 & 2047;
#pragma unroll
            for (int ni = 0; ni < 4; ++ni) {
                int col = colBase + wn * 64 + ni * 16 + l15;
                int hh = col >> 6, dd = col & 63;
                ushort4 pk;
                pk.x = f2bu(acc[mi][ni][0]); pk.y = f2bu(acc[mi][ni][1]);
                pk.z = f2bu(acc[mi][ni][2]); pk.w = f2bu(acc[mi][ni][3]);
                *(ushort4*)(Vt + (((size_t)bb * 16 + hh) * 64 + dd) * SEQ + s0) = pk;
            }
        }
    }
}

// ---------------------------------------------------------------------------
// Output projection: out[M,1024] = CTX @ Wo^T, fp32 out.
// Round-8: same T1 XCD remap (nwg=512): xcd=id&7, slot=id>>3,
// ty = xcd*8 + (slot>>3), tx = slot&7. Bijective; A panels now XCD-local.
// ---------------------------------------------------------------------------
__global__ __launch_bounds__(256) void out_gemm(const unsigned short* __restrict__ X,
                                                const unsigned short* __restrict__ W,
                                                float* __restrict__ Y) {
    __shared__ short As[128 * 32];
    __shared__ short Bs[128 * 32];

    const int id = (int)blockIdx.x + 8 * (int)blockIdx.y;
    const int xcd = id & 7, slot = id >> 3;
    const int ty = xcd * 8 + (slot >> 3);
    const int tx = slot & 7;

    const int tid = threadIdx.x;
    const int w = tid >> 6, lane = tid & 63, quad = lane >> 4, l15 = lane & 15;
    const int wm = w & 1, wn = w >> 1;
    const int rowBase = ty * 128;
    const int colBase = tx * 128;

    f32x4 acc[4][4];
#pragma unroll
    for (int mi = 0; mi < 4; ++mi)
#pragma unroll
        for (int ni = 0; ni < 4; ++ni)
#pragma unroll
            for (int e = 0; e < 4; ++e) acc[mi][ni][e] = 0.f;

    for (int k0 = 0; k0 < 1024; k0 += 32) {
        __syncthreads();
#pragma unroll
        for (int l = 0; l < 2; ++l) {
            int c = tid + l * 256;
            int row = c >> 2, ccs = c & 3;
            int cc = ccs ^ ((row >> 1) & 3);
            async16((char*)As + c * 16, X + (size_t)(rowBase + row) * 1024 + k0 + cc * 8);
            async16((char*)Bs + c * 16, W + (size_t)(colBase + row) * 1024 + k0 + cc * 8);
        }
        __syncthreads();

        bf16x8 a[4], b[4];
#pragma unroll
        for (int mi = 0; mi < 4; ++mi) {
            int r = wm * 64 + mi * 16 + l15;
            int slt = quad ^ ((r >> 1) & 3);
            a[mi] = *(const bf16x8*)&As[r * 32 + slt * 8];
        }
#pragma unroll
        for (int ni = 0; ni < 4; ++ni) {
            int r = wn * 64 + ni * 16 + l15;
            int slt = quad ^ ((r >> 1) & 3);
            b[ni] = *(const bf16x8*)&Bs[r * 32 + slt * 8];
        }
#pragma unroll
        for (int mi = 0; mi < 4; ++mi)
#pragma unroll
            for (int ni = 0; ni < 4; ++ni)
                acc[mi][ni] = __builtin_amdgcn_mfma_f32_16x16x32_bf16(a[mi], b[ni], acc[mi][ni], 0, 0, 0);
    }

#pragma unroll
    for (int mi = 0; mi < 4; ++mi)
#pragma unroll
        for (int ni = 0; ni < 4; ++ni)
#pragma unroll
            for (int reg = 0; reg < 4; ++reg) {
                int row = rowBase + wm * 64 + mi * 16 + quad * 4 + reg;
                int col = colBase + wn * 64 + ni * 16 + l15;
                Y[(size_t)row * 1024 + col] = acc[mi][ni][reg];
            }
}

// ---------------------------------------------------------------------------
// Flash attention — byte-identical to round 5 (PASSED, 124.2 us):
//   KVBLK=64, St[2], paired q-tiles {15-pid,pid} (36 iters, perfect balance),
//   XCD-local grid (64,8), double-buffered K/V with ONE barrier per tile,
//   wave-uniform triangle guards, defer-max THR=8, v_cvt_pk pack,
//   allSeq fast path, setprio around MFMA clusters.
// (V-direct-from-global is a confirmed dead end: r6/r7 both failed with
//  identical absmax 6.078 despite address-algebra equivalence. Do not retry
//  without an on-device debug probe.)
// ---------------------------------------------------------------------------
__global__ __launch_bounds__(256) void flash32(const unsigned short* __restrict__ Q,
                                               const unsigned short* __restrict__ K,
                                               const unsigned short* __restrict__ Vt,
                                               const int* __restrict__ mask,
                                               unsigned short* __restrict__ CTX) {
    __shared__ short lds[16384];           // K dbuf [0..8191], V dbuf [8192..16383] (shorts)
    __shared__ float biasS[2][64];
    __shared__ int allokS[2];
    __shared__ int okW[4];

    const int bh = blockIdx.x;             // 0..63 (same-bh blocks share an XCD)
    const int pid = blockIdx.y;            // 0..7
    const int b = bh >> 4;
    const int tid = threadIdx.x;
    const int w = tid >> 6, lane = tid & 63, l31 = lane & 31, lane5 = lane >> 5;

    const size_t qkBase = (size_t)b * SEQ * D_MODEL + (size_t)(bh & 15) * HEAD_DIM;
    const size_t vtBase = (size_t)bh * HEAD_DIM * SEQ;

    // ---- attention_mask is k-loop invariant: scan it once per block ----
    {
        int ok = 1;
        for (int i = tid; i < SEQ; i += 256) ok &= (mask[b * SEQ + i] != 0);
        unsigned long long bal = __ballot(ok != 0);
        if (lane == 0) okW[w] = (bal == ~0ull) ? 1 : 0;
    }
    __syncthreads();
    const int allSeq = okW[0] & okW[1] & okW[2] & okW[3];   // block-uniform

    // per-thread staging constants (chunk c = tid + l*256)
    int stp[2], stcc[2], stj[2];
#pragma unroll
    for (int l = 0; l < 2; ++l) {
        int c = tid + l * 256;
        int p = c >> 3, sl = c & 7;
        stp[l] = p;
        stcc[l] = sl ^ (p & 7);                                   // bank swizzle
        stj[l] = (p & 0x33) | ((p & 4) << 1) | ((p & 8) >> 1);    // swap bits 2,3
    }

    for (int phase = 0; phase < 2; ++phase) {
        const int qt = phase ? pid : 15 - pid;
        const int q0 = qt * 128;
        const int iq = q0 + w * 32 + l31;      // this lane's query row

        // Q fragments direct from global: B[n=i=l31][k=lane5*8+jj]
        bf16x8 qf[4];
#pragma unroll
        for (int ks = 0; ks < 4; ++ks)
            qf[ks] = *(const bf16x8*)(Q + qkBase + (size_t)iq * D_MODEL + ks * 16 + lane5 * 8);

        float mv = -INFINITY, lv = 0.f;
        f32x16 Ot[2];
#pragma unroll
        for (int dt = 0; dt < 2; ++dt)
#pragma unroll
            for (int e = 0; e < 16; ++e) Ot[dt][e] = 0.f;

        const int ktmax = 2 * qt + 1;

        uint4 kreg[2], vreg[2];
        int mreg = 1;
        // prefetch tile 0
#pragma unroll
        for (int l = 0; l < 2; ++l) {
            kreg[l] = *(const uint4*)(K + qkBase + (size_t)stj[l] * D_MODEL + stcc[l] * 8);
            vreg[l] = *(const uint4*)(Vt + vtBase + (size_t)stp[l] * SEQ + stcc[l] * 8);
        }
        if (!allSeq && tid < 64) mreg = mask[b * SEQ + tid];

        for (int kt = 0; kt <= ktmax; ++kt) {
            const int k0 = kt * 64;
            const int buf = kt & 1;
            // ---- stage tile kt into buf (regs -> LDS), prefetch kt+1 ----
#pragma unroll
            for (int l = 0; l < 2; ++l) {
                int c = tid + l * 256;
                *(uint4*)((char*)lds + buf * 8192 + c * 16) = kreg[l];
                *(uint4*)((char*)lds + 16384 + buf * 8192 + c * 16) = vreg[l];
            }
            if (!allSeq && tid < 64) {
                biasS[buf][tid] = mreg ? 0.f : -INFINITY;
                unsigned long long bal = __ballot(mreg != 0);
                if (tid == 0) allokS[buf] = (bal == ~0ull) ? 1 : 0;
            }
            if (kt < ktmax) {                  // prefetch next tile (overlaps compute)
                const int kn = k0 + 64;
#pragma unroll
                for (int l = 0; l < 2; ++l) {
                    kreg[l] = *(const uint4*)(K + qkBase + (size_t)(kn + stj[l]) * D_MODEL + stcc[l] * 8);
                    vreg[l] = *(const uint4*)(Vt + vtBase + (size_t)stp[l] * SEQ + kn + stcc[l] * 8);
                }
                if (!allSeq && tid < 64) mreg = mask[b * SEQ + kn + tid];
            }
            __syncthreads();                   // buf visible; buf reuse fenced by barrier(kt+1)

            if (64 * kt > q0 + 32 * w + 31) continue;   // wave-uniform: tile above causal diag

            const short* Ks = lds + buf * 4096;
            const short* Vs = lds + 8192 + buf * 4096;

            // wave-uniform active range (diagonal tile triangle)
            const int kHi = q0 + 32 * w + 31 - k0;           // >= 0 here
            const int nT = (kHi >= 32) ? 2 : 1;              // active 32-key QK sub-tiles
            const int nt = ((kHi >> 4) >= 3 ? 3 : (kHi >> 4)) + 1;  // active 16-key PV slots

            // ---- St = K Q^T (up to 8 MFMAs) -----------------------------
            f32x16 St[2];
            __builtin_amdgcn_s_setprio(1);
#pragma unroll
            for (int T = 0; T < 2; ++T) {
                if (T < nT) {
#pragma unroll
                    for (int e = 0; e < 16; ++e) St[T][e] = 0.f;
#pragma unroll
                    for (int ks = 0; ks < 4; ++ks) {
                        int p = T * 32 + l31;
                        int slot = (ks * 2 + lane5) ^ (p & 7);
                        bf16x8 a = *(const bf16x8*)&Ks[p * 64 + slot * 8];
                        St[T] = __builtin_amdgcn_mfma_f32_32x32x16_bf16(a, qf[ks], St[T], 0, 0, 0);
                    }
                }
            }
            __builtin_amdgcn_s_setprio(0);

            // ---- masking ------------------------------------------------
            const bool partial = (k0 + 63 > q0 + 32 * w);
            if (partial) {
#pragma unroll
                for (int T = 0; T < 2; ++T)
                    if (T < nT)
#pragma unroll
                        for (int r = 0; r < 16; ++r) {
                            int j = k0 + 32 * T + 16 * (r >> 3) + 8 * lane5 + (r & 7);
                            if (j > iq) St[T][r] = -INFINITY;
                        }
            }
            if (!allSeq && !allokS[buf]) {
#pragma unroll
                for (int T = 0; T < 2; ++T)
                    if (T < nT)
#pragma unroll
                        for (int r = 0; r < 16; ++r)
                            St[T][r] += biasS[buf][32 * T + 16 * (r >> 3) + 8 * lane5 + (r & 7)];
            }

            // ---- online softmax (defer-max THR=8, per-lane state) -------
            float tm[2];
#pragma unroll
            for (int T = 0; T < 2; ++T) {
                if (T < nT) {
                    float a0 = fmaxf(fmaxf(St[T][0], St[T][1]), fmaxf(St[T][2], St[T][3]));
                    float a1 = fmaxf(fmaxf(St[T][4], St[T][5]), fmaxf(St[T][6], St[T][7]));
                    float a2 = fmaxf(fmaxf(St[T][8], St[T][9]), fmaxf(St[T][10], St[T][11]));
                    float a3 = fmaxf(fmaxf(St[T][12], St[T][13]), fmaxf(St[T][14], St[T][15]));
                    tm[T] = fmaxf(fmaxf(a0, a1), fmaxf(a2, a3));
                } else tm[T] = -INFINITY;
            }
            float rm = fmaxf(tm[0], tm[1]);
            rm = fmaxf(rm, __shfl_xor(rm, 32));
            float mn = fmaxf(mv, rm);
            if (mn > mv + 8.f) {               // rare after warmup (also hits 1st tile)
                float al = exp2f(mv - mn);     // mv=-inf -> 0: correctly zeroes lv/Ot
                lv *= al;
#pragma unroll
                for (int dt = 0; dt < 2; ++dt)
#pragma unroll
                    for (int e = 0; e < 16; ++e) Ot[dt][e] *= al;
                mv = mn;
            }
            // exp2 vs (possibly stale) mv: P bounded by 2^8; -inf scores -> 0
            float rsp[2] = {0.f, 0.f};
#pragma unroll
            for (int T = 0; T < 2; ++T) {
                if (T < nT) {
#pragma unroll
                    for (int r = 0; r < 16; ++r) {
                        float pv = exp2f(St[T][r] - mv);
                        St[T][r] = pv;
                        rsp[T] += pv;
                    }
                }
            }
            float rs = rsp[0] + rsp[1];
            rs += __shfl_xor(rs, 32);
            lv += rs;

            // ---- pack P via v_cvt_pk_bf16_f32 (regs already B-frag order)
            bf16x8 pf[4];
#pragma unroll
            for (int t = 0; t < 4; ++t) {
                if (t < nt) {
                    const int T = t >> 1, hb = t & 1;
                    unsigned u0, u1, u2, u3;
                    asm("v_cvt_pk_bf16_f32 %0, %1, %2" : "=v"(u0)
                        : "v"(St[T][hb * 8 + 0]), "v"(St[T][hb * 8 + 1]));
                    asm("v_cvt_pk_bf16_f32 %0, %1, %2" : "=v"(u1)
                        : "v"(St[T][hb * 8 + 2]), "v"(St[T][hb * 8 + 3]));
                    asm("v_cvt_pk_bf16_f32 %0, %1, %2" : "=v"(u2)
                        : "v"(St[T][hb * 8 + 4]), "v"(St[T][hb * 8 + 5]));
                    asm("v_cvt_pk_bf16_f32 %0, %1, %2" : "=v"(u3)
                        : "v"(St[T][hb * 8 + 6]), "v"(St[T][hb * 8 + 7]));
                    union { unsigned u[4]; bf16x8 v; } pk;
                    pk.u[0] = u0; pk.u[1] = u1; pk.u[2] = u2; pk.u[3] = u3;
                    pf[t] = pk.v;
                }
            }

            // ---- Ot += V^T P^T (up to 8 MFMAs) --------------------------
            __builtin_amdgcn_s_setprio(1);
#pragma unroll
            for (int dt = 0; dt < 2; ++dt)
#pragma unroll
                for (int t = 0; t < 4; ++t) {
                    if (t < nt) {
                        int p = dt * 32 + l31;
                        int slot = (t * 2 + lane5) ^ (p & 7);
                        bf16x8 a = *(const bf16x8*)&Vs[p * 64 + slot * 8];
                        Ot[dt] = __builtin_amdgcn_mfma_f32_32x32x16_bf16(a, pf[t], Ot[dt], 0, 0, 0);
                    }
                }
            __builtin_amdgcn_s_setprio(0);
        }

        // ---- epilogue: normalize, transpose via LDS, coalesced store ----
        __syncthreads();                       // all waves done with K/V buffers
        const float inv = 1.f / lv;
#pragma unroll
        for (int dt = 0; dt < 2; ++dt)
#pragma unroll
            for (int k = 0; k < 8; ++k) {
                int r0 = 2 * k;
                int d = (r0 & 3) + 4 * lane5 + 8 * (r0 >> 2) + 32 * dt;
                unsigned lo = f2bu(Ot[dt][r0] * inv);
                unsigned hi = f2bu(Ot[dt][r0 + 1] * inv);
                *(unsigned*)&lds[(w * 32 + l31) * 72 + d] = lo | (hi << 16);
            }
        __syncthreads();
#pragma unroll
        for (int k = 0; k < 4; ++k) {
            int id = tid + k * 256;
            int r = id >> 3, cc = id & 7;
            uint4 v = *(const uint4*)&lds[r * 72 + cc * 8];
            *(uint4*)(CTX + qkBase + (size_t)(q0 + r) * D_MODEL + cc * 8) = v;
        }
        __syncthreads();                       // protect epilogue reads from next phase's staging
    }
}

// ---------------------------------------------------------------------------
extern "C" void kernel_launch(void* const* d_in, const int* in_sizes, int n_in,
                              void* d_out, int out_size, void* d_ws, size_t ws_size,
                              hipStream_t stream) {
    const float* x  = (const float*)d_in[0];
    const int* mask = (const int*)d_in[1];
    const float* wq = (const float*)d_in[2];
    const float* wk = (const float*)d_in[3];
    const float* wv = (const float*)d_in[4];
    const float* wo = (const float*)d_in[5];
    float* out = (float*)d_out;

    const size_t NE = (size_t)M_TOTAL * D_MODEL;
    const size_t WE = (size_t)D_MODEL * D_MODEL;
    unsigned short* ws  = (unsigned short*)d_ws;
    unsigned short* xb  = ws;
    unsigned short* wqb = xb + NE;
    unsigned short* wkb = wqb + WE;
    unsigned short* wvb = wkb + WE;
    unsigned short* wob = wvb + WE;
    unsigned short* Qb  = wob + WE;
    unsigned short* Kb  = Qb + NE;
    unsigned short* Vtb = Kb + NE;
    unsigned short* CTX = Vtb + NE;

    cast_all<<<(int)((NE + 4 * WE) / 4 / 256), 256, 0, stream>>>(x, wq, wk, wv, wo, ws);

    qkv_gemm<<<dim3(24, M_TOTAL / 128), 256, 0, stream>>>(xb, wqb, wkb, wvb, Qb, Kb, Vtb);

    flash32<<<dim3(64, 8), 256, 0, stream>>>(Qb, Kb, Vtb, mask, CTX);

    out_gemm<<<dim3(D_MODEL / 128, M_TOTAL / 128), 256, 0, stream>>>(CTX, wob, out);
}